// Round 5
// baseline (454.201 us; speedup 1.0000x reference)
//
#include <hip/hip_runtime.h>
#include <hip/hip_fp16.h>
#include <math.h>

#define NNODES 50000
#define NEDGES 800000
#define NTOT   (NNODES + NEDGES)
#define NB     ((NNODES + 1023) / 1024)
#define GROWS  96

typedef _Float16 half8 __attribute__((ext_vector_type(8)));
typedef _Float16 half4 __attribute__((ext_vector_type(4)));
typedef float    f32x4 __attribute__((ext_vector_type(4)));

// ---------------- CSR build ----------------

__global__ __launch_bounds__(256) void hist_kernel(const int* __restrict__ ei,
                                                   int* __restrict__ counts) {
  int e = blockIdx.x * 256 + threadIdx.x;
  if (e >= NTOT) return;
  int dst = (e < NEDGES) ? ei[NEDGES + e] : (e - NEDGES);
  atomicAdd(&counts[dst], 1);
}

__global__ __launch_bounds__(1024) void scan_blk(const int* __restrict__ counts,
                                                 int* __restrict__ indptr,
                                                 int* __restrict__ btot) {
  __shared__ int wsum[16];
  __shared__ int wpre[16];
  int t = threadIdx.x;
  int lane = t & 63, w = t >> 6;
  int i = blockIdx.x * 1024 + t;
  int v = (i < NNODES) ? counts[i] : 0;
  int x = v;
  #pragma unroll
  for (int off = 1; off < 64; off <<= 1) {
    int y = __shfl_up(x, off, 64);
    if (lane >= off) x += y;
  }
  if (lane == 63) wsum[w] = x;
  __syncthreads();
  if (t < 16) {
    int s = wsum[t];
    int xs = s;
    #pragma unroll
    for (int off = 1; off < 16; off <<= 1) {
      int y = __shfl_up(xs, off, 16);
      if (t >= off) xs += y;
    }
    wpre[t] = xs - s;
    if (t == 15) btot[blockIdx.x] = xs;
  }
  __syncthreads();
  if (i < NNODES) indptr[i] = wpre[w] + (x - v);
}

__global__ __launch_bounds__(64) void scan_btot(int* __restrict__ btot,
                                                int* __restrict__ indptr) {
  int t = threadIdx.x;
  int v = (t < NB) ? btot[t] : 0;
  int x = v;
  #pragma unroll
  for (int off = 1; off < 64; off <<= 1) {
    int y = __shfl_up(x, off, 64);
    if (t >= off) x += y;
  }
  if (t < NB) btot[t] = x - v;
  if (t == 0) indptr[NNODES] = NTOT;
}

__global__ __launch_bounds__(256) void add_base(int* __restrict__ indptr,
                                                const int* __restrict__ bbase,
                                                int* __restrict__ cursor) {
  int i = blockIdx.x * 256 + threadIdx.x;
  if (i >= NNODES) return;
  int v = indptr[i] + bbase[i >> 10];
  indptr[i] = v;
  cursor[i] = v;
}

__global__ __launch_bounds__(256) void scatter_kernel(const int* __restrict__ ei,
                                                      int* __restrict__ cursor,
                                                      int* __restrict__ csrc) {
  int e = blockIdx.x * 256 + threadIdx.x;
  if (e >= NTOT) return;
  int src, dst;
  if (e < NEDGES) { src = ei[e]; dst = ei[NEDGES + e]; }
  else            { src = e - NEDGES; dst = src; }
  int pos = atomicAdd(&cursor[dst], 1);
  csrc[pos] = src;
}

// ---------------- W prep (all 4 layers): fp32 W[k][n] -> fp16 hi/lo Wt[n][k] ----------------

__global__ __launch_bounds__(256) void wprep4_kernel(
    const float* __restrict__ W0, const float* __restrict__ W1,
    const float* __restrict__ W2, const float* __restrict__ W3,
    _Float16* __restrict__ hi, _Float16* __restrict__ lo) {
  int id = blockIdx.x * 256 + threadIdx.x;   // 65536 = 4 x 128 x 128
  int l = id >> 14, o = id & 16383;
  const float* W = (l == 0) ? W0 : (l == 1) ? W1 : (l == 2) ? W2 : W3;
  int n = o >> 7, k = o & 127;
  float v = W[k * 128 + n];
  _Float16 h = (_Float16)v;
  hi[id] = h;
  lo[id] = (_Float16)(v - (float)h);
}

// ---------------- GEMM via f16 MFMA, hi/lo compensated, W read from L2 ----------------
// block 384 thr = 6 waves x 16 rows = 96 rows; all 128 cols per wave (8 tiles).
// No LDS: W fragments are L1/L2-resident (64 KB total), read per MFMA operand.

__global__ __launch_bounds__(384) void gemm_mfma_kernel(
    const float* __restrict__ X, const _Float16* __restrict__ Wthi,
    const _Float16* __restrict__ Wtlo,
    const float* __restrict__ a_src, const float* __restrict__ a_dst,
    _Float16* __restrict__ Hh, float* __restrict__ alps, float* __restrict__ alpd) {
  int t = threadIdx.x;
  int wave = t >> 6, lane = t & 63;
  int row  = blockIdx.x * GROWS + wave * 16 + (lane & 15);
  int kg   = (lane >> 4) * 8;
  bool valid = row < NNODES;

  const _Float16* whp = Wthi + (lane & 15) * 128 + kg;
  const _Float16* wlp = Wtlo + (lane & 15) * 128 + kg;

  f32x4 acc[8];
  #pragma unroll
  for (int tl = 0; tl < 8; ++tl) acc[tl] = (f32x4){0.f, 0.f, 0.f, 0.f};

  #pragma unroll
  for (int kt = 0; kt < 4; ++kt) {
    int k0 = kt * 32 + kg;
    half8 bh, bl;
    if (valid) {
      const float* xp = X + (size_t)row * 128 + k0;
      float4 f0 = *(const float4*)xp;
      float4 f1 = *(const float4*)(xp + 4);
      float fv[8] = {f0.x, f0.y, f0.z, f0.w, f1.x, f1.y, f1.z, f1.w};
      #pragma unroll
      for (int j = 0; j < 8; ++j) {
        _Float16 h = (_Float16)fv[j];
        bh[j] = h;
        bl[j] = (_Float16)(fv[j] - (float)h);
      }
    } else {
      #pragma unroll
      for (int j = 0; j < 8; ++j) { bh[j] = (_Float16)0.f; bl[j] = (_Float16)0.f; }
    }
    #pragma unroll
    for (int tl = 0; tl < 8; ++tl) {
      int off = tl * 2048 + kt * 32;   // (tl*16 rows) * 128 + kt*32, in halves
      half8 ah = *(const half8*)(whp + off);
      half8 al = *(const half8*)(wlp + off);
      acc[tl] = __builtin_amdgcn_mfma_f32_16x16x32_f16(ah, bh, acc[tl], 0, 0, 0);
      acc[tl] = __builtin_amdgcn_mfma_f32_16x16x32_f16(ah, bl, acc[tl], 0, 0, 0);
      acc[tl] = __builtin_amdgcn_mfma_f32_16x16x32_f16(al, bh, acc[tl], 0, 0, 0);
    }
  }

  // epilogue: Hh fp16 write + alpha dot-products (fp32-exact h)
  int cg = (lane >> 4) * 4;
  float ps[4] = {0.f, 0.f, 0.f, 0.f}, pd[4] = {0.f, 0.f, 0.f, 0.f};
  #pragma unroll
  for (int tl = 0; tl < 8; ++tl) {
    int col0 = tl * 16 + cg;
    float4 as4 = *(const float4*)&a_src[col0];
    float4 ad4 = *(const float4*)&a_dst[col0];
    int hd = tl >> 1;
    ps[hd] += acc[tl][0] * as4.x + acc[tl][1] * as4.y + acc[tl][2] * as4.z + acc[tl][3] * as4.w;
    pd[hd] += acc[tl][0] * ad4.x + acc[tl][1] * ad4.y + acc[tl][2] * ad4.z + acc[tl][3] * ad4.w;
    if (valid) {
      half4 hv;
      hv[0] = (_Float16)acc[tl][0]; hv[1] = (_Float16)acc[tl][1];
      hv[2] = (_Float16)acc[tl][2]; hv[3] = (_Float16)acc[tl][3];
      *(half4*)&Hh[(size_t)row * 128 + col0] = hv;
    }
  }
  #pragma unroll
  for (int hd = 0; hd < 4; ++hd) {
    ps[hd] += __shfl_xor(ps[hd], 16, 64);
    ps[hd] += __shfl_xor(ps[hd], 32, 64);
    pd[hd] += __shfl_xor(pd[hd], 16, 64);
    pd[hd] += __shfl_xor(pd[hd], 32, 64);
  }
  if (valid && lane < 16) {
    *(f32x4*)&alps[row * 4] = (f32x4){ps[0], ps[1], ps[2], ps[3]};
    *(f32x4*)&alpd[row * 4] = (f32x4){pd[0], pd[1], pd[2], pd[3]};
  }
}

// ---------------- aggregation: one wave per dst node, no-max softmax ----------------
// phase A: lane = edge, p = exp(min(e,60)) for 4 heads (|e|<~3, exact vs ref).
// phase B: 32 channel-lanes x 2 edges per iteration, half4 gathers.

__global__ __launch_bounds__(256) void agg_kernel(
    const __half* __restrict__ Hh, const float* __restrict__ alps,
    const float* __restrict__ alpd, const int* __restrict__ indptr,
    const int* __restrict__ csrc, const float* __restrict__ bias,
    float* __restrict__ out, int relu_flag) {
  __shared__ float p_lds[4][64 * 4];
  __shared__ int   s_lds[4][64];
  int wslot = threadIdx.x >> 6;
  int wid = (blockIdx.x * 256 + threadIdx.x) >> 6;
  if (wid >= NNODES) return;
  int lane = threadIdx.x & 63;
  int e2   = lane >> 5;           // which edge of the pair (phase B)
  int cidx = lane & 31;           // channel group: 4 channels
  int hd_b = cidx >> 3;           // head for phase B
  int col0 = cidx * 4;
  int beg = indptr[wid];
  int cnt = indptr[wid + 1] - beg;

  float4 adv = *(const float4*)(&alpd[wid * 4]);

  float s0 = 0.f, s1 = 0.f, s2 = 0.f, s3 = 0.f;
  float a0 = 0.f, a1 = 0.f, a2 = 0.f, a3 = 0.f;

  for (int base = 0; base < cnt; base += 64) {
    int nc = min(64, cnt - base);
    // ---- phase A: per-lane edge, p = exp(e) for all 4 heads ----
    float p0 = 0.f, p1 = 0.f, p2 = 0.f, p3 = 0.f;
    int src = 0;
    if (lane < nc) {
      src = csrc[beg + base + lane];
      float4 av = *(const float4*)(&alps[src * 4]);
      float v0 = av.x + adv.x, v1 = av.y + adv.y;
      float v2 = av.z + adv.z, v3 = av.w + adv.w;
      float e0 = (v0 > 0.f) ? v0 : 0.2f * v0;
      float e1 = (v1 > 0.f) ? v1 : 0.2f * v1;
      float e2v = (v2 > 0.f) ? v2 : 0.2f * v2;
      float e3 = (v3 > 0.f) ? v3 : 0.2f * v3;
      p0 = __expf(fminf(e0, 60.f));
      p1 = __expf(fminf(e1, 60.f));
      p2 = __expf(fminf(e2v, 60.f));
      p3 = __expf(fminf(e3, 60.f));
    }
    s_lds[wslot][lane] = src;
    *(float4*)(&p_lds[wslot][lane * 4]) = make_float4(p0, p1, p2, p3);
    // denominator sums (wave-uniform after butterfly)
    float q0 = p0, q1 = p1, q2 = p2, q3 = p3;
    #pragma unroll
    for (int off = 1; off < 64; off <<= 1) {
      q0 += __shfl_xor(q0, off, 64);
      q1 += __shfl_xor(q1, off, 64);
      q2 += __shfl_xor(q2, off, 64);
      q3 += __shfl_xor(q3, off, 64);
    }
    s0 += q0; s1 += q1; s2 += q2; s3 += q3;
    asm volatile("s_waitcnt lgkmcnt(0)" ::: "memory");  // wave-local LDS RAW
    // ---- phase B: 2 edges per iteration ----
    #pragma unroll 4
    for (int j = 0; j < nc; j += 2) {
      int jj = j + e2;                      // jj==nc (odd tail) reads p=0 slot
      int sj  = s_lds[wslot][jj];
      float pj = p_lds[wslot][jj * 4 + hd_b];
      const half4 hv4 = *(const half4*)(&Hh[(size_t)sj * 128 + col0]);
      a0 = fmaf(pj, (float)hv4[0], a0);
      a1 = fmaf(pj, (float)hv4[1], a1);
      a2 = fmaf(pj, (float)hv4[2], a2);
      a3 = fmaf(pj, (float)hv4[3], a3);
    }
  }

  // combine the two edge-groups
  a0 += __shfl_xor(a0, 32, 64);
  a1 += __shfl_xor(a1, 32, 64);
  a2 += __shfl_xor(a2, 32, 64);
  a3 += __shfl_xor(a3, 32, 64);

  if (lane < 32) {
    float sh = (hd_b == 0) ? s0 : (hd_b == 1) ? s1 : (hd_b == 2) ? s2 : s3;
    float inv = 1.0f / sh;
    float4 bv = *(const float4*)(&bias[col0]);
    float o0 = a0 * inv + bv.x;
    float o1 = a1 * inv + bv.y;
    float o2 = a2 * inv + bv.z;
    float o3 = a3 * inv + bv.w;
    if (relu_flag) {
      o0 = fmaxf(o0, 0.f); o1 = fmaxf(o1, 0.f);
      o2 = fmaxf(o2, 0.f); o3 = fmaxf(o3, 0.f);
    }
    *(float4*)(&out[(size_t)wid * 128 + col0]) = make_float4(o0, o1, o2, o3);
  }
}

// ---------------- launch ----------------

extern "C" void kernel_launch(void* const* d_in, const int* in_sizes, int n_in,
                              void* d_out, int out_size, void* d_ws, size_t ws_size,
                              hipStream_t stream) {
  const float* x  = (const float*)d_in[0];
  const int*   ei = (const int*)d_in[1];
  const float* W[4]  = {(const float*)d_in[2],  (const float*)d_in[6],
                        (const float*)d_in[10], (const float*)d_in[14]};
  const float* As[4] = {(const float*)d_in[3],  (const float*)d_in[7],
                        (const float*)d_in[11], (const float*)d_in[15]};
  const float* Ad[4] = {(const float*)d_in[4],  (const float*)d_in[8],
                        (const float*)d_in[12], (const float*)d_in[16]};
  const float* Bs[4] = {(const float*)d_in[5],  (const float*)d_in[9],
                        (const float*)d_in[13], (const float*)d_in[17]};

  char* p = (char*)d_ws;
  auto alloc = [&](size_t bytes) {
    char* r = p;
    p += (bytes + 255) & ~(size_t)255;
    return r;
  };
  int*      cursor = (int*)alloc(sizeof(int) * NNODES);
  int*      indptr = (int*)alloc(sizeof(int) * (NNODES + 1));
  int*      csrc   = (int*)alloc(sizeof(int) * NTOT);
  int*      btot   = (int*)alloc(sizeof(int) * 64);
  float*    alps   = (float*)alloc(sizeof(float) * NNODES * 4);
  float*    alpd   = (float*)alloc(sizeof(float) * NNODES * 4);
  float*    bufA   = (float*)alloc(sizeof(float) * (size_t)NNODES * 128);
  _Float16* Hh     = (_Float16*)alloc(sizeof(_Float16) * (size_t)NNODES * 128);
  _Float16* Wthi   = (_Float16*)alloc(sizeof(_Float16) * 4 * 128 * 128);
  _Float16* Wtlo   = (_Float16*)alloc(sizeof(_Float16) * 4 * 128 * 128);

  hipMemsetAsync(cursor, 0, sizeof(int) * NNODES, stream);
  hist_kernel   <<<(NTOT + 255) / 256, 256, 0, stream>>>(ei, cursor);
  scan_blk      <<<NB, 1024, 0, stream>>>(cursor, indptr, btot);
  scan_btot     <<<1, 64, 0, stream>>>(btot, indptr);
  add_base      <<<(NNODES + 255) / 256, 256, 0, stream>>>(indptr, btot, cursor);
  scatter_kernel<<<(NTOT + 255) / 256, 256, 0, stream>>>(ei, cursor, csrc);
  wprep4_kernel <<<256, 256, 0, stream>>>(W[0], W[1], W[2], W[3], Wthi, Wtlo);

  const float* cur = x;
  for (int l = 0; l < 4; ++l) {
    gemm_mfma_kernel<<<(NNODES + GROWS - 1) / GROWS, 384, 0, stream>>>(
        cur, Wthi + l * 16384, Wtlo + l * 16384, As[l], Ad[l], Hh, alps, alpd);
    float* o = (l == 3) ? (float*)d_out : bufA;
    agg_kernel<<<(NNODES * 64 + 255) / 256, 256, 0, stream>>>(
        (const __half*)Hh, alps, alpd, indptr, csrc, Bs[l], o, (l < 3) ? 1 : 0);
    cur = o;
  }
}